// Round 3
// baseline (123.644 us; speedup 1.0000x reference)
//
#include <hip/hip_runtime.h>
#include <hip/hip_bf16.h>

// Problem constants (from reference): B=64, T=8000, S=10.
#define B_ 64
#define T_ 8000
#define S_ 10
#define NCHUNK 8             // T split into 8 chunks of 1000 t's
#define TPC 1000             // t's per chunk
#define ACTIVE 250           // threads 0..249 each own 4 consecutive t's

// ws layout: partial : [B][NCHUNK][112] floats (110 used: M[100] then D[10])

// ---------------------------------------------------------------------------
// Kernel 1: M[i][j] = sum_t (logp - log1mp)[t,i] * tgt[t,j],  D[i] = sum_t log1mp[t,i]
// grid (NCHUNK, B) x 256. Thread tid<250 owns 4 consecutive t's, processed as
// 2 rounds of 2 t's (5 float4 per input per round).
// CRITICAL: loads go into NAMED float4 vars, then scalar arrays are
// brace-initialized from components -- every array index is static, no
// reinterpret_cast stores, so SROA keeps everything in VGPRs. (R1's
// punned-pointer fill put pr/tg/acc in scratch: VGPR_Count=88, 55us
// latency-bound at 4% HBM.)
// ---------------------------------------------------------------------------
__global__ __launch_bounds__(256, 2) void pit_cost_kernel(
    const float* __restrict__ pred, const float* __restrict__ tgt,
    float* __restrict__ partial, float* __restrict__ out)
{
    const int b     = blockIdx.y;
    const int chunk = blockIdx.x;
    const int tid   = threadIdx.x;

    if (b == 0 && chunk == 0 && tid == 0) out[0] = 0.0f;

    float acc[110];
#pragma unroll
    for (int v = 0; v < 110; ++v) acc[v] = 0.0f;

    if (tid < ACTIVE) {
        // 4 t's = 40 floats = ten float4's per input, split into 2 rounds.
        const size_t off = (size_t)b * (T_ * S_) + (size_t)chunk * (TPC * S_)
                         + (size_t)tid * 40;
        const float4* P = reinterpret_cast<const float4*>(pred + off);
        const float4* G = reinterpret_cast<const float4*>(tgt + off);

#pragma unroll
        for (int r = 0; r < 2; ++r) {
            const float4 pA = P[r * 5 + 0], pB = P[r * 5 + 1], pC = P[r * 5 + 2],
                         pD = P[r * 5 + 3], pE = P[r * 5 + 4];
            const float4 gA = G[r * 5 + 0], gB = G[r * 5 + 1], gC = G[r * 5 + 2],
                         gD = G[r * 5 + 3], gE = G[r * 5 + 4];
            const float pr[20] = {pA.x, pA.y, pA.z, pA.w, pB.x, pB.y, pB.z, pB.w,
                                  pC.x, pC.y, pC.z, pC.w, pD.x, pD.y, pD.z, pD.w,
                                  pE.x, pE.y, pE.z, pE.w};
            const float tg[20] = {gA.x, gA.y, gA.z, gA.w, gB.x, gB.y, gB.z, gB.w,
                                  gC.x, gC.y, gC.z, gC.w, gD.x, gD.y, gD.z, gD.w,
                                  gE.x, gE.y, gE.z, gE.w};
#pragma unroll
            for (int u = 0; u < 2; ++u) {
                float d[10];
#pragma unroll
                for (int i = 0; i < 10; ++i) {
                    const float pv = pr[u * 10 + i];
                    const float lm = __logf(1.0f - pv);   // log(1-p)
                    d[i] = __logf(pv) - lm;               // logit(p)
                    acc[100 + i] += lm;                   // D[i]
                }
#pragma unroll
                for (int i = 0; i < 10; ++i) {
#pragma unroll
                    for (int j = 0; j < 10; ++j) {
                        acc[i * 10 + j] += d[i] * tg[u * 10 + j];  // M[i][j]
                    }
                }
            }
        }
    }

    // Block reduction: per-wave butterfly, then cross-wave sum through LDS.
    __shared__ float red[4][112];
    const int wave = tid >> 6;
    const int lane = tid & 63;
#pragma unroll
    for (int v = 0; v < 110; ++v) {
        float x = acc[v];
#pragma unroll
        for (int off = 32; off > 0; off >>= 1) x += __shfl_xor(x, off, 64);
        if (lane == 0) red[wave][v] = x;
    }
    __syncthreads();
    if (tid < 110) {
        const float s = red[0][tid] + red[1][tid] + red[2][tid] + red[3][tid];
        partial[((size_t)b * NCHUNK + chunk) * 112 + tid] = s;
    }
}

// ---------------------------------------------------------------------------
// Kernel 2: per batch b -- cost[i][j] = -(M[i][j] + D[i]); exact assignment
// via subset DP over column masks; atomicAdd normalized optimum into out[0].
// ---------------------------------------------------------------------------
__global__ __launch_bounds__(256, 1) void pit_dp_kernel(
    const float* __restrict__ partial, float* __restrict__ out)
{
    const int b   = blockIdx.x;
    const int tid = threadIdx.x;

    __shared__ float sum[112];
    __shared__ float cost[100];
    __shared__ float dp[1024];

    if (tid < 110) {
        const float* pb = partial + (size_t)b * NCHUNK * 112;
        float s = 0.0f;
#pragma unroll
        for (int c = 0; c < NCHUNK; ++c) s += pb[c * 112 + tid];
        sum[tid] = s;
    }
    __syncthreads();
    if (tid < 100) cost[tid] = -(sum[tid] + sum[100 + tid / 10]);
    if (tid == 0) dp[0] = 0.0f;
    __syncthreads();

    for (int k = 1; k <= 10; ++k) {
        for (int m = tid; m < 1024; m += 256) {
            if (__popc(m) == k) {
                float best = 3.0e38f;
#pragma unroll
                for (int j = 0; j < 10; ++j) {
                    if (m & (1 << j)) {
                        const float c = dp[m ^ (1 << j)] + cost[(k - 1) * 10 + j];
                        best = fminf(best, c);
                    }
                }
                dp[m] = best;
            }
        }
        __syncthreads();
    }
    if (tid == 0) {
        atomicAdd(out, dp[1023] * (1.0f / ((float)T_ * (float)B_ * (float)S_)));
    }
}

extern "C" void kernel_launch(void* const* d_in, const int* in_sizes, int n_in,
                              void* d_out, int out_size, void* d_ws, size_t ws_size,
                              hipStream_t stream)
{
    const float* pred = (const float*)d_in[0];
    const float* tgt  = (const float*)d_in[1];
    float* partial = (float*)d_ws;          // [64][8][112] floats (~229 KB)
    float* out     = (float*)d_out;

    pit_cost_kernel<<<dim3(NCHUNK, B_), 256, 0, stream>>>(pred, tgt, partial, out);
    pit_dp_kernel<<<B_, 256, 0, stream>>>(partial, out);
}